// Round 9
// baseline (3572.969 us; speedup 1.0000x reference)
//
#include <hip/hip_runtime.h>
#include <cstdint>
#include <cstddef>

typedef __bf16 bf16_t;
typedef bf16_t bf16x4 __attribute__((ext_vector_type(4)));
typedef bf16_t bf16x8 __attribute__((ext_vector_type(8)));
typedef float  f32x4  __attribute__((ext_vector_type(4)));

#define LAYERS 4
#define DMODEL 768
#define NHEAD  12
#define DHEAD  64
#define MFEAT  64
#define FFDIM  3072
#define BB     8
#define SSEQ   2048
#define BSROWS (BB*SSEQ)          /* 16384 */
#define QROWS  (BSROWS*NHEAD)     /* 196608 */
#define FFCHUNK (BSROWS/2)        /* 8192 rows per FF chunk */
#define SCH    16                 /* s-chunks for ctx */
#define SPC    (SSEQ/SCH)         /* 128 s per chunk */
#define NBH    (BB*NHEAD)         /* 96 */

// async global->LDS, 16B per lane (dest must be linear in lane order)
__device__ __forceinline__ void gload_lds16(const bf16_t* g, bf16_t* l) {
    __builtin_amdgcn_global_load_lds(
        (const __attribute__((address_space(1))) uint32_t*)g,
        (__attribute__((address_space(3))) uint32_t*)l, 16, 0, 0);
}

// ---------------------------------------------------------------------------
// Transpose + cast: in (K,N) f32 row-major -> out (N,K) bf16 row-major
// ---------------------------------------------------------------------------
__global__ __launch_bounds__(256) void castT_kernel(
    const float* __restrict__ in, bf16_t* __restrict__ out, int K, int N)
{
    __shared__ float t[32][33];
    int kb = blockIdx.x * 32, nb = blockIdx.y * 32;
    int tx = threadIdx.x & 31, ty = threadIdx.x >> 5;   // ty 0..7
#pragma unroll
    for (int i = 0; i < 32; i += 8)
        t[ty + i][tx] = in[(size_t)(kb + ty + i) * N + nb + tx];
    __syncthreads();
#pragma unroll
    for (int i = 0; i < 32; i += 8)
        out[(size_t)(nb + ty + i) * K + kb + tx] = (bf16_t)t[tx][ty + i];
}

// P (M,DH) f32 -> bf16 scaled by DH^-0.25 (folds dn into both qp and kp GEMMs)
__global__ __launch_bounds__(256) void castP_kernel(
    const float* __restrict__ in, bf16_t* __restrict__ out)
{
    int i = blockIdx.x * 256 + threadIdx.x;  // 4096 total
    out[i] = (bf16_t)(in[i] * 0.3535533905932738f);
}

// concat per-layer q/k/v biases -> bqkv[l][2304]
__global__ __launch_bounds__(256) void biascat_kernel(
    const float* __restrict__ bq, const float* __restrict__ bk,
    const float* __restrict__ bv, float* __restrict__ out)
{
    int i = blockIdx.x * 256 + threadIdx.x;   // LAYERS*2304 = 9216
    int l = i / 2304, j = i % 2304;
    float v = (j < 768) ? bq[l * 768 + j]
            : (j < 1536) ? bk[l * 768 + j - 768]
                         : bv[l * 768 + j - 1536];
    out[i] = v;
}

// ---------------------------------------------------------------------------
// Fused shift_tokens + LayerNorm: x f32 (B,S,D) -> out bf16 (B,S,D)
// ---------------------------------------------------------------------------
template<bool MASKED>
__global__ __launch_bounds__(256) void shiftln_kernel(
    const float* __restrict__ x, const int* __restrict__ ids,
    const float* __restrict__ g, const float* __restrict__ bl,
    bf16_t* __restrict__ out)
{
    const int r = blockIdx.x;          // b*S+s
    const int b = r >> 11;             // S=2048
    const int s = r & 2047;
    const int tid = threadIdx.x;
    float v0, v1, v2;
    {
        int s2 = s + 1;
        bool ok = (s2 < SSEQ) && (!MASKED || ids[b * SSEQ + s2] == 0);
        v0 = ok ? x[((size_t)(b * SSEQ + s2)) * DMODEL + tid] : 0.f;
    }
    v1 = x[((size_t)r) * DMODEL + tid + 256];
    {
        int s2 = s - 1;
        bool ok = (s2 >= 0) && (!MASKED || ids[b * SSEQ + s2] == 0);
        v2 = ok ? x[((size_t)(b * SSEQ + s2)) * DMODEL + tid + 512] : 0.f;
    }
    float sum = v0 + v1 + v2;
    float sq  = v0 * v0 + v1 * v1 + v2 * v2;
#pragma unroll
    for (int off = 32; off; off >>= 1) {
        sum += __shfl_down(sum, off);
        sq  += __shfl_down(sq, off);
    }
    __shared__ float red[2][4];
    int lane = tid & 63, w = tid >> 6;
    if (lane == 0) { red[0][w] = sum; red[1][w] = sq; }
    __syncthreads();
    sum = red[0][0] + red[0][1] + red[0][2] + red[0][3];
    sq  = red[1][0] + red[1][1] + red[1][2] + red[1][3];
    float mu  = sum * (1.f / DMODEL);
    float var = sq * (1.f / DMODEL) - mu * mu;
    float rstd = rsqrtf(var + 1e-5f);
    size_t base = (size_t)r * DMODEL;
    out[base + tid]       = (bf16_t)((v0 - mu) * rstd * g[tid]       + bl[tid]);
    out[base + tid + 256] = (bf16_t)((v1 - mu) * rstd * g[tid + 256] + bl[tid + 256]);
    out[base + tid + 512] = (bf16_t)((v2 - mu) * rstd * g[tid + 512] + bl[tid + 512]);
}

// ---------------------------------------------------------------------------
// bf16 MFMA GEMM: C(rows,N) = A(rows,K) @ Bt(N,K)^T
// BK=64, global_load_lds width-16 staging (linear LDS dest, INVERSE-swizzled
// global source), XOR-swizzled ds_read_b128 (conflict-free), XCD-aware
// block remap. 4 waves in 2x2; wave-tile = (BM/2)x(BN/2). Epilogues:
//  2: relu(acc)+eps -> bf16 (no bias)
//  3: +bias, gelu   -> bf16
//  4: +bias, +resid -> f32  (resid may alias outp; elementwise)
//  5: fused qkv     -> bf16 (thirds route to q/k/v, v-mask via ids)
// ---------------------------------------------------------------------------
template<int BM, int BN, int EPI>
__global__ __launch_bounds__(256) void gemm_kernel(
    const bf16_t* __restrict__ A, const bf16_t* __restrict__ Bt,
    const float* __restrict__ bias, const float* resid,
    const int* __restrict__ ids, void* outp,
    int N, int K)
{
    constexpr int BK = 64;
    constexpr int WM = BM / 2, WN = BN / 2;
    constexpr int AM = WM / 16, AN = WN / 16;
    __shared__ bf16_t As[BM * BK];
    __shared__ bf16_t Bs[BN * BK];
    const int tid  = threadIdx.x;
    const int lane = tid & 63, wid = tid >> 6;
    const int wr = wid >> 1, wc = wid & 1;
    // XCD-aware bijective remap (all grids here have nwg % 8 == 0)
    const int gx = gridDim.x;
    const int nwg = gx * (int)gridDim.y;
    int orig = (int)blockIdx.y * gx + (int)blockIdx.x;
    int wgid = orig;
    if ((nwg & 7) == 0) wgid = (orig & 7) * (nwg >> 3) + (orig >> 3);
    const int rowBase = (wgid / gx) * BM;
    const int colBase = (wgid % gx) * BN;

    f32x4 acc[AM][AN];
#pragma unroll
    for (int i = 0; i < AM; i++)
#pragma unroll
        for (int j = 0; j < AN; j++) { f32x4 z = {0.f,0.f,0.f,0.f}; acc[i][j] = z; }

    const int rl = lane & 15;
    const int c0 = lane >> 4;       // 16B-chunk sub-index 0..3
    const int sx = rl & 7;          // row-XOR swizzle key

    for (int k0 = 0; k0 < K; k0 += BK) {
        __syncthreads();
        // stage: LDS dest linear in lane order, global source inverse-swizzled
#pragma unroll
        for (int i = 0; i < (BM * 8) / 256; i++) {
            int idx = i * 256 + tid;
            int row = idx >> 3, ccp = idx & 7;
            int ccl = ccp ^ (row & 7);
            gload_lds16(&A[(size_t)(rowBase + row) * K + k0 + ccl * 8], &As[idx * 8]);
        }
#pragma unroll
        for (int i = 0; i < (BN * 8) / 256; i++) {
            int idx = i * 256 + tid;
            int row = idx >> 3, ccp = idx & 7;
            int ccl = ccp ^ (row & 7);
            gload_lds16(&Bt[(size_t)(colBase + row) * K + k0 + ccl * 8], &Bs[idx * 8]);
        }
        __syncthreads();   // drains vmcnt -> staged data visible
#pragma unroll
        for (int kk = 0; kk < 2; kk++) {
            const int ccp = ((kk << 2) | c0) ^ sx;
            bf16x8 af[AM], bfr[AN];
#pragma unroll
            for (int i = 0; i < AM; i++)
                af[i] = *(const bf16x8*)&As[(wr * WM + i * 16 + rl) * BK + ccp * 8];
#pragma unroll
            for (int j = 0; j < AN; j++)
                bfr[j] = *(const bf16x8*)&Bs[(wc * WN + j * 16 + rl) * BK + ccp * 8];
#pragma unroll
            for (int i = 0; i < AM; i++)
#pragma unroll
                for (int j = 0; j < AN; j++)
                    acc[i][j] = __builtin_amdgcn_mfma_f32_16x16x32_bf16(
                        af[i], bfr[j], acc[i][j], 0, 0, 0);
        }
    }

#pragma unroll
    for (int i = 0; i < AM; i++)
#pragma unroll
        for (int j = 0; j < AN; j++) {
            int col = colBase + wc * WN + j * 16 + rl;
#pragma unroll
            for (int r4 = 0; r4 < 4; r4++) {
                int row = rowBase + wr * WM + i * 16 + (lane >> 4) * 4 + r4;
                float v = acc[i][j][r4];
                if constexpr (EPI == 2) {
                    float o = v > 0.f ? v : 0.f;
                    ((bf16_t*)outp)[(size_t)row * N + col] = (bf16_t)(o + 0.001f);
                } else if constexpr (EPI == 3) {
                    float xg = v + bias[col];
                    float o = 0.5f * xg * (1.f + erff(xg * 0.70710678118654752f));
                    ((bf16_t*)outp)[(size_t)row * N + col] = (bf16_t)o;
                } else if constexpr (EPI == 4) {
                    size_t idx = (size_t)row * N + col;
                    ((float*)outp)[idx] = v + bias[col] + resid[idx];
                } else {  // EPI == 5: fused qkv
                    int third = col / DMODEL;          // uniform per block (BN|768)
                    int colq  = col - third * DMODEL;
                    float o = v + bias[col];
                    if (third == 2 && ids[row] != 0) o = 0.f;
                    bf16_t* ob = (bf16_t*)outp + (size_t)third * BSROWS * DMODEL;
                    ob[(size_t)row * DMODEL + colq] = (bf16_t)o;
                }
            }
        }
}

// ---------------------------------------------------------------------------
// ctx partial: block = (bh, s-chunk). Stages kp/v tiles converted to f32 in
// LDS, accumulates partial ctx[m,d] over 128 s, plus ks partial (dg==0).
// part layout: [chunk][bh][m*64+d]; ksp: [chunk][bh][m]
// ---------------------------------------------------------------------------
__global__ __launch_bounds__(256) void ctx_partial_kernel(
    const bf16_t* __restrict__ kp, const bf16_t* __restrict__ v,
    float* __restrict__ part, float* __restrict__ ksp)
{
    const int blk = blockIdx.x;
    const int bh = blk / SCH, chunk = blk % SCH;
    const int b = bh / NHEAD, h = bh % NHEAD;
    __shared__ float kpf[SPC][64];
    __shared__ float vf[SPC][64];
    const int tid = threadIdx.x;
#pragma unroll
    for (int i = 0; i < 4; i++) {
        int idx = tid + i * 256;          // 8-elem chunk id
        int sl = idx >> 3, c = (idx & 7) * 8;
        size_t go = ((size_t)(b * SSEQ + chunk * SPC + sl) * NHEAD + h) * 64 + c;
        bf16x8 kv8 = *(const bf16x8*)&kp[go];
        bf16x8 vv8 = *(const bf16x8*)&v[go];
#pragma unroll
        for (int e = 0; e < 8; e++) {
            kpf[sl][c + e] = (float)kv8[e];
            vf[sl][c + e]  = (float)vv8[e];
        }
    }
    __syncthreads();
    const int m = tid & 63, dg = tid >> 6;
    float ksacc = 0.f;
    f32x4 acc[4];
#pragma unroll
    for (int jg = 0; jg < 4; jg++) { f32x4 z = {0.f,0.f,0.f,0.f}; acc[jg] = z; }
    for (int sl = 0; sl < SPC; sl++) {
        float kv = kpf[sl][m];
        ksacc += kv;
#pragma unroll
        for (int jg = 0; jg < 4; jg++) {
            f32x4 c4 = *(const f32x4*)&vf[sl][dg * 16 + jg * 4];
            acc[jg] += kv * c4;
        }
    }
    size_t obase = ((size_t)chunk * NBH + bh) * 4096 + (size_t)m * 64 + dg * 16;
#pragma unroll
    for (int jg = 0; jg < 4; jg++)
#pragma unroll
        for (int e = 0; e < 4; e++) part[obase + jg * 4 + e] = acc[jg][e];
    if (dg == 0) ksp[((size_t)chunk * NBH + bh) * 64 + m] = ksacc;
}

// ctxb[bh][e] = sum_chunk part[chunk][bh][e]
__global__ __launch_bounds__(256) void ctx_reduce_kernel(
    const float* __restrict__ part, float* __restrict__ ctxb)
{
    int e = blockIdx.x * 256 + threadIdx.x;    // 96*4096 total
    float s = 0.f;
#pragma unroll
    for (int c = 0; c < SCH; c++) s += part[(size_t)c * NBH * 4096 + e];
    ctxb[e] = s;
}

// ---------------------------------------------------------------------------
// out[b,s,h*64+d] = (1/(qp·ks)) * sum_m qp[b,s,h,m]*ctx[b,h,m,d]
// ---------------------------------------------------------------------------
__global__ __launch_bounds__(256) void attnout_kernel(
    const bf16_t* __restrict__ qp, const float* __restrict__ ctx,
    const float* __restrict__ ksp, bf16_t* __restrict__ out)
{
    const int blk = blockIdx.x;
    const int sc = blk & 31;          // S/64 = 32
    const int bh = blk >> 5;
    const int b = bh / NHEAD, h = bh % NHEAD;
    __shared__ float ctxs[64][64];
    __shared__ float kss[64];
    const int tid = threadIdx.x;
#pragma unroll
    for (int i = 0; i < 16; i++) {
        int flat = tid + i * 256;
        ctxs[flat >> 6][flat & 63] = ctx[(size_t)bh * 4096 + flat];
    }
    if (tid < 64) {
        float s = 0.f;
#pragma unroll
        for (int c = 0; c < SCH; c++) s += ksp[((size_t)c * NBH + bh) * 64 + tid];
        kss[tid] = s;
    }
    __syncthreads();
    const int sl = tid >> 2, dg = tid & 3;
    const int s = sc * 64 + sl;
    const bf16_t* qrow = &qp[((size_t)(b * SSEQ + s) * NHEAD + h) * 64];
    float den = 0.f;
    f32x4 acc[4];
#pragma unroll
    for (int jg = 0; jg < 4; jg++) { f32x4 z = {0.f,0.f,0.f,0.f}; acc[jg] = z; }
#pragma unroll 4
    for (int m = 0; m < 64; m++) {
        float qv = (float)qrow[m];
        den += qv * kss[m];
#pragma unroll
        for (int jg = 0; jg < 4; jg++) {
            f32x4 c4 = *(const f32x4*)&ctxs[m][dg * 16 + jg * 4];
            acc[jg] += qv * c4;
        }
    }
    float inv = 1.f / den;
    size_t obase = (size_t)(b * SSEQ + s) * DMODEL + h * 64 + dg * 16;
#pragma unroll
    for (int jg = 0; jg < 4; jg++)
#pragma unroll
        for (int e = 0; e < 4; e++)
            out[obase + jg * 4 + e] = (bf16_t)(acc[jg][e] * inv);
}

// ---------------------------------------------------------------------------
__global__ void avg_kernel(const float* __restrict__ a, const float* __restrict__ b,
                           float* __restrict__ o, int n4)
{
    for (int i = blockIdx.x * 256 + threadIdx.x; i < n4; i += gridDim.x * 256) {
        f32x4 av = ((const f32x4*)a)[i];
        f32x4 bv = ((const f32x4*)b)[i];
        ((f32x4*)o)[i] = (av + bv) * 0.5f;
    }
}

// ---------------------------------------------------------------------------
extern "C" void kernel_launch(void* const* d_in, const int* in_sizes, int n_in,
                              void* d_out, int out_size, void* d_ws, size_t ws_size,
                              hipStream_t stream)
{
    int idi = 1, base = 2;
    if (in_sizes[1] != BSROWS) { idi = n_in - 1; base = 1; }
    const float* x_f   = (const float*)d_in[0];
    const int*   ids   = (const int*)d_in[idi];
    const float* Wq    = (const float*)d_in[base + 0];
    const float* bq    = (const float*)d_in[base + 1];
    const float* Wk    = (const float*)d_in[base + 2];
    const float* bk    = (const float*)d_in[base + 3];
    const float* Wv    = (const float*)d_in[base + 4];
    const float* bv    = (const float*)d_in[base + 5];
    const float* Wo    = (const float*)d_in[base + 6];
    const float* bo    = (const float*)d_in[base + 7];
    const float* ln1g  = (const float*)d_in[base + 8];
    const float* ln1b  = (const float*)d_in[base + 9];
    const float* W1    = (const float*)d_in[base + 10];
    const float* b1    = (const float*)d_in[base + 11];
    const float* W2    = (const float*)d_in[base + 12];
    const float* b2    = (const float*)d_in[base + 13];
    const float* ln2g  = (const float*)d_in[base + 14];
    const float* ln2b  = (const float*)d_in[base + 15];
    const float* proj  = (const float*)d_in[base + 16];

    // ---- workspace carve (~162.5 MiB; x1 stream lives in d_out) ----
    char* p = (char*)d_ws;
    auto alloc = [&](size_t bytes) -> char* {
        char* r = p; p += (bytes + 255) & ~(size_t)255; return r;
    };
    float*  r1   = (float*)d_out;                                    // x1 stream
    float*  r2   = (float*)alloc((size_t)BSROWS * DMODEL * 4);       // x2 stream
    bf16_t* hbuf = (bf16_t*)alloc((size_t)BSROWS * DMODEL * 2);      // h / attn_out / ctx partials
    char*   ub   = alloc((size_t)3 * BSROWS * DMODEL * 2);           // {qb,kb,vb} | gff
    bf16_t* qb   = (bf16_t*)ub;                                      // qkv contiguous
    bf16_t* kb   = (bf16_t*)(ub + (size_t)BSROWS * DMODEL * 2);
    bf16_t* vb   = (bf16_t*)(ub + (size_t)2 * BSROWS * DMODEL * 2);
    bf16_t* gff  = (bf16_t*)ub;
    float*  ctxb = (float*)alloc((size_t)NBH * 64 * 64 * 4);
    float*  ksp  = (float*)alloc((size_t)SCH * NBH * 64 * 4);        // ks partials
    char*   wu   = alloc((size_t)2 * DMODEL * FFDIM * 2);            // attn | ff weights
    bf16_t* wqkvt = (bf16_t*)wu;                                     // 2304 x 768
    bf16_t* wot  = (bf16_t*)(wu + (size_t)3 * DMODEL * DMODEL * 2);
    bf16_t* w1t  = (bf16_t*)wu;
    bf16_t* w2t  = (bf16_t*)(wu + (size_t)DMODEL * FFDIM * 2);
    bf16_t* pb   = (bf16_t*)alloc((size_t)MFEAT * DHEAD * 2);
    float*  bqkv = (float*)alloc((size_t)LAYERS * 2304 * 4);
    float*  ctxpart = (float*)hbuf;   // 16*96*4096*4 B == BSROWS*DMODEL*2 B

    biascat_kernel<<<(LAYERS * 2304) / 256, 256, 0, stream>>>(bq, bk, bv, bqkv);

    const float* c1 = x_f;
    const float* c2 = x_f;

    for (int l = 0; l < LAYERS; l++) {
        // ---- attention weights: concat-transposed qkv + wo ----
        castT_kernel<<<dim3(24, 24), 256, 0, stream>>>(Wq + (size_t)l * DMODEL * DMODEL, wqkvt, DMODEL, DMODEL);
        castT_kernel<<<dim3(24, 24), 256, 0, stream>>>(Wk + (size_t)l * DMODEL * DMODEL, wqkvt + (size_t)DMODEL * DMODEL, DMODEL, DMODEL);
        castT_kernel<<<dim3(24, 24), 256, 0, stream>>>(Wv + (size_t)l * DMODEL * DMODEL, wqkvt + (size_t)2 * DMODEL * DMODEL, DMODEL, DMODEL);
        castT_kernel<<<dim3(24, 24), 256, 0, stream>>>(Wo + (size_t)l * DMODEL * DMODEL, wot, DMODEL, DMODEL);
        castP_kernel<<<16, 256, 0, stream>>>(proj + (size_t)l * MFEAT * DHEAD, pb);

        // ---- attention ----
        shiftln_kernel<true><<<BSROWS, 256, 0, stream>>>(
            c2, ids, ln1g + l * DMODEL, ln1b + l * DMODEL, hbuf);
        // fused qkv: N=2304, routes thirds to qb/kb/vb (+v mask)
        gemm_kernel<256, 128, 5><<<dim3(2304 / 128, BSROWS / 256), 256, 0, stream>>>(
            hbuf, wqkvt, bqkv + l * 2304, nullptr, ids, qb, 2304, DMODEL);
        gemm_kernel<128, 64, 2><<<dim3(1, QROWS / 128), 256, 0, stream>>>(
            qb, pb, nullptr, nullptr, nullptr, qb, MFEAT, DHEAD);
        gemm_kernel<128, 64, 2><<<dim3(1, QROWS / 128), 256, 0, stream>>>(
            kb, pb, nullptr, nullptr, nullptr, kb, MFEAT, DHEAD);
        ctx_partial_kernel<<<NBH * SCH, 256, 0, stream>>>(kb, vb, ctxpart, ksp);
        ctx_reduce_kernel<<<(NBH * 4096) / 256, 256, 0, stream>>>(ctxpart, ctxb);
        attnout_kernel<<<NBH * (SSEQ / 64), 256, 0, stream>>>(qb, ctxb, ksp, hbuf);
        gemm_kernel<256, 128, 4><<<dim3(DMODEL / 128, BSROWS / 256), 256, 0, stream>>>(
            hbuf, wot, bo + l * DMODEL, c1, nullptr, r1, DMODEL, DMODEL);
        c1 = r1;

        // ---- FF weights (attn weights dead now) ----
        castT_kernel<<<dim3(24, 96), 256, 0, stream>>>(W1 + (size_t)l * DMODEL * FFDIM, w1t, DMODEL, FFDIM);
        castT_kernel<<<dim3(96, 24), 256, 0, stream>>>(W2 + (size_t)l * FFDIM * DMODEL, w2t, FFDIM, DMODEL);

        // ---- feed-forward (2 row-chunks so gff fits the qkv union) ----
        shiftln_kernel<false><<<BSROWS, 256, 0, stream>>>(
            c1, ids, ln2g + l * DMODEL, ln2b + l * DMODEL, hbuf);
        for (int ch = 0; ch < 2; ch++) {
            const bf16_t* hA = hbuf + (size_t)ch * FFCHUNK * DMODEL;
            gemm_kernel<256, 128, 3><<<dim3(FFDIM / 128, FFCHUNK / 256), 256, 0, stream>>>(
                hA, w1t, b1 + l * FFDIM, nullptr, nullptr, gff, FFDIM, DMODEL);
            gemm_kernel<256, 128, 4><<<dim3(DMODEL / 128, FFCHUNK / 256), 256, 0, stream>>>(
                gff, w2t, b2 + l * DMODEL, c2 + (size_t)ch * FFCHUNK * DMODEL, nullptr,
                r2 + (size_t)ch * FFCHUNK * DMODEL, DMODEL, FFDIM);
        }
        c2 = r2;
    }

    avg_kernel<<<4096, 256, 0, stream>>>(c1, c2, (float*)d_out,
                                         (BSROWS * DMODEL) / 4);
}

// Round 10
// 2544.672 us; speedup vs baseline: 1.4041x; 1.4041x over previous
//
#include <hip/hip_runtime.h>
#include <cstdint>
#include <cstddef>

typedef __bf16 bf16_t;
typedef bf16_t bf16x4 __attribute__((ext_vector_type(4)));
typedef bf16_t bf16x8 __attribute__((ext_vector_type(8)));
typedef float  f32x4  __attribute__((ext_vector_type(4)));

#define LAYERS 4
#define DMODEL 768
#define NHEAD  12
#define DHEAD  64
#define MFEAT  64
#define FFDIM  3072
#define BB     8
#define SSEQ   2048
#define BSROWS (BB*SSEQ)          /* 16384 */
#define QROWS  (BSROWS*NHEAD)     /* 196608 */
#define FFCHUNK (BSROWS/2)        /* 8192 rows per FF chunk */
#define SCH    16                 /* s-chunks for ctx */
#define SPC    (SSEQ/SCH)         /* 128 s per chunk */
#define NBH    (BB*NHEAD)         /* 96 */

// async global->LDS, 16B per lane (dest must be linear in lane order)
__device__ __forceinline__ void gload_lds16(const bf16_t* g, bf16_t* l) {
    __builtin_amdgcn_global_load_lds(
        (const __attribute__((address_space(1))) uint32_t*)g,
        (__attribute__((address_space(3))) uint32_t*)l, 16, 0, 0);
}

// ---------------------------------------------------------------------------
// Transpose + cast: in (K,N) f32 row-major -> out (N,K) bf16 row-major
// ---------------------------------------------------------------------------
__global__ __launch_bounds__(256) void castT_kernel(
    const float* __restrict__ in, bf16_t* __restrict__ out, int K, int N)
{
    __shared__ float t[32][33];
    int kb = blockIdx.x * 32, nb = blockIdx.y * 32;
    int tx = threadIdx.x & 31, ty = threadIdx.x >> 5;   // ty 0..7
#pragma unroll
    for (int i = 0; i < 32; i += 8)
        t[ty + i][tx] = in[(size_t)(kb + ty + i) * N + nb + tx];
    __syncthreads();
#pragma unroll
    for (int i = 0; i < 32; i += 8)
        out[(size_t)(nb + ty + i) * K + kb + tx] = (bf16_t)t[tx][ty + i];
}

// P (M,DH) f32 -> bf16 scaled by DH^-0.25 (folds dn into both qp and kp GEMMs)
__global__ __launch_bounds__(256) void castP_kernel(
    const float* __restrict__ in, bf16_t* __restrict__ out)
{
    int i = blockIdx.x * 256 + threadIdx.x;  // 4096 total
    out[i] = (bf16_t)(in[i] * 0.3535533905932738f);
}

// concat per-layer q/k/v biases -> bqkv[l][2304]
__global__ __launch_bounds__(256) void biascat_kernel(
    const float* __restrict__ bq, const float* __restrict__ bk,
    const float* __restrict__ bv, float* __restrict__ out)
{
    int i = blockIdx.x * 256 + threadIdx.x;   // LAYERS*2304 = 9216
    int l = i / 2304, j = i % 2304;
    float v = (j < 768) ? bq[l * 768 + j]
            : (j < 1536) ? bk[l * 768 + j - 768]
                         : bv[l * 768 + j - 1536];
    out[i] = v;
}

// ---------------------------------------------------------------------------
// Fused shift_tokens + LayerNorm: x f32 (B,S,D) -> out bf16 (B,S,D)
// ---------------------------------------------------------------------------
template<bool MASKED>
__global__ __launch_bounds__(256) void shiftln_kernel(
    const float* __restrict__ x, const int* __restrict__ ids,
    const float* __restrict__ g, const float* __restrict__ bl,
    bf16_t* __restrict__ out)
{
    const int r = blockIdx.x;          // b*S+s
    const int b = r >> 11;             // S=2048
    const int s = r & 2047;
    const int tid = threadIdx.x;
    float v0, v1, v2;
    {
        int s2 = s + 1;
        bool ok = (s2 < SSEQ) && (!MASKED || ids[b * SSEQ + s2] == 0);
        v0 = ok ? x[((size_t)(b * SSEQ + s2)) * DMODEL + tid] : 0.f;
    }
    v1 = x[((size_t)r) * DMODEL + tid + 256];
    {
        int s2 = s - 1;
        bool ok = (s2 >= 0) && (!MASKED || ids[b * SSEQ + s2] == 0);
        v2 = ok ? x[((size_t)(b * SSEQ + s2)) * DMODEL + tid + 512] : 0.f;
    }
    float sum = v0 + v1 + v2;
    float sq  = v0 * v0 + v1 * v1 + v2 * v2;
#pragma unroll
    for (int off = 32; off; off >>= 1) {
        sum += __shfl_down(sum, off);
        sq  += __shfl_down(sq, off);
    }
    __shared__ float red[2][4];
    int lane = tid & 63, w = tid >> 6;
    if (lane == 0) { red[0][w] = sum; red[1][w] = sq; }
    __syncthreads();
    sum = red[0][0] + red[0][1] + red[0][2] + red[0][3];
    sq  = red[1][0] + red[1][1] + red[1][2] + red[1][3];
    float mu  = sum * (1.f / DMODEL);
    float var = sq * (1.f / DMODEL) - mu * mu;
    float rstd = rsqrtf(var + 1e-5f);
    size_t base = (size_t)r * DMODEL;
    out[base + tid]       = (bf16_t)((v0 - mu) * rstd * g[tid]       + bl[tid]);
    out[base + tid + 256] = (bf16_t)((v1 - mu) * rstd * g[tid + 256] + bl[tid + 256]);
    out[base + tid + 512] = (bf16_t)((v2 - mu) * rstd * g[tid + 512] + bl[tid + 512]);
}

// ---------------------------------------------------------------------------
// bf16 MFMA GEMM: C(rows,N) = A(rows,K) @ Bt(N,K)^T
// 128x128, BK=64, 4 waves 2x2 (R7 geometry, known-good) + 2-phase
// double-buffered K-loop: stage tile t+1 into alt LDS buffer BEFORE the
// ds_read+MFMA of tile t; single __syncthreads per K-step (its implicit
// vmcnt(0) drain + barrier provide both cross-buffer fences).
// global_load_lds width-16 (linear LDS dest, inverse-swizzled global src),
// XOR-swizzled ds_read_b128 (conflict-free), XCD-aware block remap.
// Epilogues:
//  2: relu(acc)+eps -> bf16 (no bias)
//  3: +bias, gelu   -> bf16
//  4: +bias, +resid -> f32  (resid may alias outp; elementwise)
//  5: fused qkv     -> bf16 (thirds route to q/k/v, v-mask via ids)
// ---------------------------------------------------------------------------
template<int BM, int BN, int EPI>
__global__ __launch_bounds__(256) void gemm_kernel(
    const bf16_t* __restrict__ A, const bf16_t* __restrict__ Bt,
    const float* __restrict__ bias, const float* resid,
    const int* __restrict__ ids, void* outp,
    int N, int K)
{
    constexpr int BK = 64;
    constexpr int WM = BM / 2, WN = BN / 2;
    constexpr int AM = WM / 16, AN = WN / 16;
    __shared__ bf16_t As[2][BM * BK];
    __shared__ bf16_t Bs[2][BN * BK];
    const int tid  = threadIdx.x;
    const int lane = tid & 63, wid = tid >> 6;
    const int wr = wid >> 1, wc = wid & 1;
    // XCD-aware bijective remap (all grids here have nwg % 8 == 0)
    const int gx = gridDim.x;
    const int nwg = gx * (int)gridDim.y;
    int orig = (int)blockIdx.y * gx + (int)blockIdx.x;
    int wgid = orig;
    if ((nwg & 7) == 0) wgid = (orig & 7) * (nwg >> 3) + (orig >> 3);
    const int rowBase = (wgid / gx) * BM;
    const int colBase = (wgid % gx) * BN;

    f32x4 acc[AM][AN];
#pragma unroll
    for (int i = 0; i < AM; i++)
#pragma unroll
        for (int j = 0; j < AN; j++) { f32x4 z = {0.f,0.f,0.f,0.f}; acc[i][j] = z; }

    const int rl = lane & 15;
    const int c0 = lane >> 4;       // 16B-chunk sub-index 0..3
    const int sx = rl & 7;          // row-XOR swizzle key

    auto stage = [&](int t, int buf) {
        const int k0 = t * BK;
#pragma unroll
        for (int i = 0; i < (BM * 8) / 256; i++) {
            int idx = i * 256 + tid;
            int row = idx >> 3, ccp = idx & 7;
            int ccl = ccp ^ (row & 7);
            gload_lds16(&A[(size_t)(rowBase + row) * K + k0 + ccl * 8],
                        &As[buf][idx * 8]);
        }
#pragma unroll
        for (int i = 0; i < (BN * 8) / 256; i++) {
            int idx = i * 256 + tid;
            int row = idx >> 3, ccp = idx & 7;
            int ccl = ccp ^ (row & 7);
            gload_lds16(&Bt[(size_t)(colBase + row) * K + k0 + ccl * 8],
                        &Bs[buf][idx * 8]);
        }
    };

    const int NT = K / BK;
    stage(0, 0);
    __syncthreads();           // drain prologue loads
    int cur = 0;
    for (int t = 0; t < NT; t++) {
        if (t + 1 < NT) stage(t + 1, cur ^ 1);   // prefetch next tile (issues fly under MFMA)
#pragma unroll
        for (int kk = 0; kk < 2; kk++) {
            const int ccp = ((kk << 2) | c0) ^ sx;
            bf16x8 af[AM], bfr[AN];
#pragma unroll
            for (int i = 0; i < AM; i++)
                af[i] = *(const bf16x8*)&As[cur][(wr * WM + i * 16 + rl) * BK + ccp * 8];
#pragma unroll
            for (int j = 0; j < AN; j++)
                bfr[j] = *(const bf16x8*)&Bs[cur][(wc * WN + j * 16 + rl) * BK + ccp * 8];
#pragma unroll
            for (int i = 0; i < AM; i++)
#pragma unroll
                for (int j = 0; j < AN; j++)
                    acc[i][j] = __builtin_amdgcn_mfma_f32_16x16x32_bf16(
                        af[i], bfr[j], acc[i][j], 0, 0, 0);
        }
        __syncthreads();       // vmcnt(0)+barrier: fences both buffers
        cur ^= 1;
    }

#pragma unroll
    for (int i = 0; i < AM; i++)
#pragma unroll
        for (int j = 0; j < AN; j++) {
            int col = colBase + wc * WN + j * 16 + rl;
#pragma unroll
            for (int r4 = 0; r4 < 4; r4++) {
                int row = rowBase + wr * WM + i * 16 + (lane >> 4) * 4 + r4;
                float v = acc[i][j][r4];
                if constexpr (EPI == 2) {
                    float o = v > 0.f ? v : 0.f;
                    ((bf16_t*)outp)[(size_t)row * N + col] = (bf16_t)(o + 0.001f);
                } else if constexpr (EPI == 3) {
                    float xg = v + bias[col];
                    float o = 0.5f * xg * (1.f + erff(xg * 0.70710678118654752f));
                    ((bf16_t*)outp)[(size_t)row * N + col] = (bf16_t)o;
                } else if constexpr (EPI == 4) {
                    size_t idx = (size_t)row * N + col;
                    ((float*)outp)[idx] = v + bias[col] + resid[idx];
                } else {  // EPI == 5: fused qkv
                    int third = col / DMODEL;          // uniform per block (BN|768)
                    int colq  = col - third * DMODEL;
                    float o = v + bias[col];
                    if (third == 2 && ids[row] != 0) o = 0.f;
                    bf16_t* ob = (bf16_t*)outp + (size_t)third * BSROWS * DMODEL;
                    ob[(size_t)row * DMODEL + colq] = (bf16_t)o;
                }
            }
        }
}

// ---------------------------------------------------------------------------
// ctx partial: block = (bh, s-chunk). Stages kp/v tiles converted to f32 in
// LDS, accumulates partial ctx[m,d] over 128 s, plus ks partial (dg==0).
// part layout: [chunk][bh][m*64+d]; ksp: [chunk][bh][m]
// ---------------------------------------------------------------------------
__global__ __launch_bounds__(256) void ctx_partial_kernel(
    const bf16_t* __restrict__ kp, const bf16_t* __restrict__ v,
    float* __restrict__ part, float* __restrict__ ksp)
{
    const int blk = blockIdx.x;
    const int bh = blk / SCH, chunk = blk % SCH;
    const int b = bh / NHEAD, h = bh % NHEAD;
    __shared__ float kpf[SPC][64];
    __shared__ float vf[SPC][64];
    const int tid = threadIdx.x;
#pragma unroll
    for (int i = 0; i < 4; i++) {
        int idx = tid + i * 256;          // 8-elem chunk id
        int sl = idx >> 3, c = (idx & 7) * 8;
        size_t go = ((size_t)(b * SSEQ + chunk * SPC + sl) * NHEAD + h) * 64 + c;
        bf16x8 kv8 = *(const bf16x8*)&kp[go];
        bf16x8 vv8 = *(const bf16x8*)&v[go];
#pragma unroll
        for (int e = 0; e < 8; e++) {
            kpf[sl][c + e] = (float)kv8[e];
            vf[sl][c + e]  = (float)vv8[e];
        }
    }
    __syncthreads();
    const int m = tid & 63, dg = tid >> 6;
    float ksacc = 0.f;
    f32x4 acc[4];
#pragma unroll
    for (int jg = 0; jg < 4; jg++) { f32x4 z = {0.f,0.f,0.f,0.f}; acc[jg] = z; }
    for (int sl = 0; sl < SPC; sl++) {
        float kv = kpf[sl][m];
        ksacc += kv;
#pragma unroll
        for (int jg = 0; jg < 4; jg++) {
            f32x4 c4 = *(const f32x4*)&vf[sl][dg * 16 + jg * 4];
            acc[jg] += kv * c4;
        }
    }
    size_t obase = ((size_t)chunk * NBH + bh) * 4096 + (size_t)m * 64 + dg * 16;
#pragma unroll
    for (int jg = 0; jg < 4; jg++)
#pragma unroll
        for (int e = 0; e < 4; e++) part[obase + jg * 4 + e] = acc[jg][e];
    if (dg == 0) ksp[((size_t)chunk * NBH + bh) * 64 + m] = ksacc;
}

// ctxb[bh][e] = sum_chunk part[chunk][bh][e]
__global__ __launch_bounds__(256) void ctx_reduce_kernel(
    const float* __restrict__ part, float* __restrict__ ctxb)
{
    int e = blockIdx.x * 256 + threadIdx.x;    // 96*4096 total
    float s = 0.f;
#pragma unroll
    for (int c = 0; c < SCH; c++) s += part[(size_t)c * NBH * 4096 + e];
    ctxb[e] = s;
}

// ---------------------------------------------------------------------------
// out[b,s,h*64+d] = (1/(qp·ks)) * sum_m qp[b,s,h,m]*ctx[b,h,m,d]
// ---------------------------------------------------------------------------
__global__ __launch_bounds__(256) void attnout_kernel(
    const bf16_t* __restrict__ qp, const float* __restrict__ ctx,
    const float* __restrict__ ksp, bf16_t* __restrict__ out)
{
    const int blk = blockIdx.x;
    const int sc = blk & 31;          // S/64 = 32
    const int bh = blk >> 5;
    const int b = bh / NHEAD, h = bh % NHEAD;
    __shared__ float ctxs[64][64];
    __shared__ float kss[64];
    const int tid = threadIdx.x;
#pragma unroll
    for (int i = 0; i < 16; i++) {
        int flat = tid + i * 256;
        ctxs[flat >> 6][flat & 63] = ctx[(size_t)bh * 4096 + flat];
    }
    if (tid < 64) {
        float s = 0.f;
#pragma unroll
        for (int c = 0; c < SCH; c++) s += ksp[((size_t)c * NBH + bh) * 64 + tid];
        kss[tid] = s;
    }
    __syncthreads();
    const int sl = tid >> 2, dg = tid & 3;
    const int s = sc * 64 + sl;
    const bf16_t* qrow = &qp[((size_t)(b * SSEQ + s) * NHEAD + h) * 64];
    float den = 0.f;
    f32x4 acc[4];
#pragma unroll
    for (int jg = 0; jg < 4; jg++) { f32x4 z = {0.f,0.f,0.f,0.f}; acc[jg] = z; }
#pragma unroll 4
    for (int m = 0; m < 64; m++) {
        float qv = (float)qrow[m];
        den += qv * kss[m];
#pragma unroll
        for (int jg = 0; jg < 4; jg++) {
            f32x4 c4 = *(const f32x4*)&ctxs[m][dg * 16 + jg * 4];
            acc[jg] += qv * c4;
        }
    }
    float inv = 1.f / den;
    size_t obase = (size_t)(b * SSEQ + s) * DMODEL + h * 64 + dg * 16;
#pragma unroll
    for (int jg = 0; jg < 4; jg++)
#pragma unroll
        for (int e = 0; e < 4; e++)
            out[obase + jg * 4 + e] = (bf16_t)(acc[jg][e] * inv);
}

// ---------------------------------------------------------------------------
__global__ void avg_kernel(const float* __restrict__ a, const float* __restrict__ b,
                           float* __restrict__ o, int n4)
{
    for (int i = blockIdx.x * 256 + threadIdx.x; i < n4; i += gridDim.x * 256) {
        f32x4 av = ((const f32x4*)a)[i];
        f32x4 bv = ((const f32x4*)b)[i];
        ((f32x4*)o)[i] = (av + bv) * 0.5f;
    }
}

// ---------------------------------------------------------------------------
extern "C" void kernel_launch(void* const* d_in, const int* in_sizes, int n_in,
                              void* d_out, int out_size, void* d_ws, size_t ws_size,
                              hipStream_t stream)
{
    int idi = 1, base = 2;
    if (in_sizes[1] != BSROWS) { idi = n_in - 1; base = 1; }
    const float* x_f   = (const float*)d_in[0];
    const int*   ids   = (const int*)d_in[idi];
    const float* Wq    = (const float*)d_in[base + 0];
    const float* bq    = (const float*)d_in[base + 1];
    const float* Wk    = (const float*)d_in[base + 2];
    const float* bk    = (const float*)d_in[base + 3];
    const float* Wv    = (const float*)d_in[base + 4];
    const float* bv    = (const float*)d_in[base + 5];
    const float* Wo    = (const float*)d_in[base + 6];
    const float* bo    = (const float*)d_in[base + 7];
    const float* ln1g  = (const float*)d_in[base + 8];
    const float* ln1b  = (const float*)d_in[base + 9];
    const float* W1    = (const float*)d_in[base + 10];
    const float* b1    = (const float*)d_in[base + 11];
    const float* W2    = (const float*)d_in[base + 12];
    const float* b2    = (const float*)d_in[base + 13];
    const float* ln2g  = (const float*)d_in[base + 14];
    const float* ln2b  = (const float*)d_in[base + 15];
    const float* proj  = (const float*)d_in[base + 16];

    // ---- workspace carve (~162.5 MiB; x1 stream lives in d_out) ----
    char* p = (char*)d_ws;
    auto alloc = [&](size_t bytes) -> char* {
        char* r = p; p += (bytes + 255) & ~(size_t)255; return r;
    };
    float*  r1   = (float*)d_out;                                    // x1 stream
    float*  r2   = (float*)alloc((size_t)BSROWS * DMODEL * 4);       // x2 stream
    bf16_t* hbuf = (bf16_t*)alloc((size_t)BSROWS * DMODEL * 2);      // h / attn_out / ctx partials
    char*   ub   = alloc((size_t)3 * BSROWS * DMODEL * 2);           // {qb,kb,vb} | gff
    bf16_t* qb   = (bf16_t*)ub;                                      // qkv contiguous
    bf16_t* kb   = (bf16_t*)(ub + (size_t)BSROWS * DMODEL * 2);
    bf16_t* vb   = (bf16_t*)(ub + (size_t)2 * BSROWS * DMODEL * 2);
    bf16_t* gff  = (bf16_t*)ub;
    float*  ctxb = (float*)alloc((size_t)NBH * 64 * 64 * 4);
    float*  ksp  = (float*)alloc((size_t)SCH * NBH * 64 * 4);        // ks partials
    char*   wu   = alloc((size_t)2 * DMODEL * FFDIM * 2);            // attn | ff weights
    bf16_t* wqkvt = (bf16_t*)wu;                                     // 2304 x 768
    bf16_t* wot  = (bf16_t*)(wu + (size_t)3 * DMODEL * DMODEL * 2);
    bf16_t* w1t  = (bf16_t*)wu;
    bf16_t* w2t  = (bf16_t*)(wu + (size_t)DMODEL * FFDIM * 2);
    bf16_t* pb   = (bf16_t*)alloc((size_t)MFEAT * DHEAD * 2);
    float*  bqkv = (float*)alloc((size_t)LAYERS * 2304 * 4);
    float*  ctxpart = (float*)hbuf;   // 16*96*4096*4 B == BSROWS*DMODEL*2 B

    biascat_kernel<<<(LAYERS * 2304) / 256, 256, 0, stream>>>(bq, bk, bv, bqkv);

    const float* c1 = x_f;
    const float* c2 = x_f;

    for (int l = 0; l < LAYERS; l++) {
        // ---- attention weights: concat-transposed qkv + wo ----
        castT_kernel<<<dim3(24, 24), 256, 0, stream>>>(Wq + (size_t)l * DMODEL * DMODEL, wqkvt, DMODEL, DMODEL);
        castT_kernel<<<dim3(24, 24), 256, 0, stream>>>(Wk + (size_t)l * DMODEL * DMODEL, wqkvt + (size_t)DMODEL * DMODEL, DMODEL, DMODEL);
        castT_kernel<<<dim3(24, 24), 256, 0, stream>>>(Wv + (size_t)l * DMODEL * DMODEL, wqkvt + (size_t)2 * DMODEL * DMODEL, DMODEL, DMODEL);
        castT_kernel<<<dim3(24, 24), 256, 0, stream>>>(Wo + (size_t)l * DMODEL * DMODEL, wot, DMODEL, DMODEL);
        castP_kernel<<<16, 256, 0, stream>>>(proj + (size_t)l * MFEAT * DHEAD, pb);

        // ---- attention ----
        shiftln_kernel<true><<<BSROWS, 256, 0, stream>>>(
            c2, ids, ln1g + l * DMODEL, ln1b + l * DMODEL, hbuf);
        // fused qkv: N=2304, routes thirds to qb/kb/vb (+v mask)
        gemm_kernel<128, 128, 5><<<dim3(2304 / 128, BSROWS / 128), 256, 0, stream>>>(
            hbuf, wqkvt, bqkv + l * 2304, nullptr, ids, qb, 2304, DMODEL);
        gemm_kernel<128, 64, 2><<<dim3(1, QROWS / 128), 256, 0, stream>>>(
            qb, pb, nullptr, nullptr, nullptr, qb, MFEAT, DHEAD);
        gemm_kernel<128, 64, 2><<<dim3(1, QROWS / 128), 256, 0, stream>>>(
            kb, pb, nullptr, nullptr, nullptr, kb, MFEAT, DHEAD);
        ctx_partial_kernel<<<NBH * SCH, 256, 0, stream>>>(kb, vb, ctxpart, ksp);
        ctx_reduce_kernel<<<(NBH * 4096) / 256, 256, 0, stream>>>(ctxpart, ctxb);
        attnout_kernel<<<NBH * (SSEQ / 64), 256, 0, stream>>>(qb, ctxb, ksp, hbuf);
        gemm_kernel<128, 128, 4><<<dim3(DMODEL / 128, BSROWS / 128), 256, 0, stream>>>(
            hbuf, wot, bo + l * DMODEL, c1, nullptr, r1, DMODEL, DMODEL);
        c1 = r1;

        // ---- FF weights (attn weights dead now) ----
        castT_kernel<<<dim3(24, 96), 256, 0, stream>>>(W1 + (size_t)l * DMODEL * FFDIM, w1t, DMODEL, FFDIM);
        castT_kernel<<<dim3(96, 24), 256, 0, stream>>>(W2 + (size_t)l * FFDIM * DMODEL, w2t, FFDIM, DMODEL);

        // ---- feed-forward (2 row-chunks so gff fits the qkv union) ----
        shiftln_kernel<false><<<BSROWS, 256, 0, stream>>>(
            c1, ids, ln2g + l * DMODEL, ln2b + l * DMODEL, hbuf);
        for (int ch = 0; ch < 2; ch++) {
            const bf16_t* hA = hbuf + (size_t)ch * FFCHUNK * DMODEL;
            gemm_kernel<128, 128, 3><<<dim3(FFDIM / 128, FFCHUNK / 128), 256, 0, stream>>>(
                hA, w1t, b1 + l * FFDIM, nullptr, nullptr, gff, FFDIM, DMODEL);
            gemm_kernel<128, 128, 4><<<dim3(DMODEL / 128, FFCHUNK / 128), 256, 0, stream>>>(
                gff, w2t, b2 + l * DMODEL, c2 + (size_t)ch * FFCHUNK * DMODEL, nullptr,
                r2 + (size_t)ch * FFCHUNK * DMODEL, DMODEL, FFDIM);
        }
        c2 = r2;
    }

    avg_kernel<<<4096, 256, 0, stream>>>(c1, c2, (float*)d_out,
                                         (BSROWS * DMODEL) / 4);
}